// Round 5
// baseline (1047.856 us; speedup 1.0000x reference)
//
#include <hip/hip_runtime.h>
#include <hip/hip_bf16.h>
#include <cstdint>

#define N_NODES 100000
#define N_EDGES 3200000

typedef __attribute__((ext_vector_type(8))) short short8;
typedef __attribute__((ext_vector_type(4))) float floatx4;

#define FXS 8388608.0f           // 2^23 fixed-point scale for degree accum
#define MASK40 0xFFFFFFFFFFull

__device__ __forceinline__ unsigned short f2bf(float f) {
    unsigned u = __float_as_uint(f);
    u += 0x7fff + ((u >> 16) & 1);          // round-to-nearest-even
    return (unsigned short)(u >> 16);
}
__device__ __forceinline__ float bf2f(unsigned short s) {
    return __uint_as_float(((unsigned)s) << 16);
}
__device__ __forceinline__ float bflo(unsigned u) {
    return __uint_as_float(u << 16);
}
__device__ __forceinline__ float bfhi(unsigned u) {
    return __uint_as_float(u & 0xffff0000u);
}
__device__ __forceinline__ unsigned pack_bf2(float a, float b) {
    union { __hip_bfloat162 h2; unsigned u; } cv;
    cv.h2 = __float22bfloat162_rn(make_float2(a, b));   // v_cvt_pk_bf16_f32
    return cv.u;
}

// ------------------------------------------------------------------
// Setup: pack WcatT[192][512] / Wc1T / Wc2T (bf16, transposed) + zero packed[]
// ------------------------------------------------------------------
__global__ void setup_misc(const float* __restrict__ W1, const float* __restrict__ b1,
                           const float* __restrict__ Ww, const float* __restrict__ bw,
                           const float* __restrict__ Wa, const float* __restrict__ ba,
                           const float* __restrict__ Wc1, const float* __restrict__ Wc2,
                           unsigned short* __restrict__ WcatT, float* __restrict__ bcat,
                           unsigned short* __restrict__ Wc1T, unsigned short* __restrict__ Wc2T,
                           unsigned long long* __restrict__ packed, int n) {
    int bid = blockIdx.x, tid = threadIdx.x;
    if (bid < 192) {
        int c = bid;
        for (int kk = tid; kk < 512; kk += 256) {
            float v;
            if (c < 128)      v = W1[kk * 128 + c];
            else if (c < 168) v = Ww[kk * 40 + (c - 128)];
            else if (c < 170) v = Wa[kk * 2 + (c - 168)];
            else              v = 0.f;
            WcatT[(size_t)c * 512 + kk] = f2bf(v);
        }
        if (tid == 0) {
            float b;
            if (c < 128)      b = b1[c];
            else if (c < 168) b = bw[c - 128];
            else if (c < 170) b = ba[c - 168];
            else              b = 0.f;
            bcat[c] = b;
        }
    } else if (bid < 320) {
        int c = bid - 192;
        if (tid < 128) Wc1T[(size_t)c * 128 + tid] = f2bf(Wc1[tid * 128 + c]);
        else { int k = tid - 128; Wc2T[(size_t)c * 128 + k] = f2bf(Wc2[k * 128 + c]); }
    } else {
        int i = (bid - 320) * 256 + tid;
        if (i < n) packed[i] = 0ull;
    }
}

// ------------------------------------------------------------------
// LDS-free MFMA bf16 GEMM body. Wave = 16 rows x (16*NT) cols.
// Block = 4 waves = 64 rows, full N width. No LDS, no barriers:
// A and B fragments are loaded directly in MFMA layout
// (frag[idx=lane&15][k=quad*8+j] == 16B/lane from row-major [idx][K]).
// B (pre-transposed weights) is tiny -> L1/L2-resident re-reads.
// EPI 0: C0 bf16 [M][128] = rowscale[m] * val
// EPI 1: n<128 -> relu+bias -> C0 bf16; n<168 -> C1 fp32; n<170 -> C2 fp32
// ------------------------------------------------------------------
template <int EPI, int NT, int AF32>
__device__ __forceinline__ void gemm_body(
    int mblk, const void* __restrict__ Avoid, const unsigned short* __restrict__ BT,
    int M, int K,
    unsigned short* __restrict__ C0, float* __restrict__ C1, float* __restrict__ C2,
    const float* __restrict__ bias, const float* __restrict__ rowscale) {
    int tid = threadIdx.x;
    int wave = tid >> 6, lane = tid & 63;
    int quad = lane >> 4, mi = lane & 15;
    int m0 = mblk * 64 + wave * 16;

    int arow = m0 + mi; if (arow >= M) arow = M - 1;

    floatx4 acc[NT] = {};

    for (int kc = 0; kc < K; kc += 32) {
        short8 a;
        if (AF32) {
            const float* Af = (const float*)Avoid;
            const float4* ap = (const float4*)(Af + (size_t)arow * K + kc + quad * 8);
            float4 f0 = ap[0], f1 = ap[1];
            union { uint4 u; short8 s; } pk;
            pk.u.x = pack_bf2(f0.x, f0.y);
            pk.u.y = pack_bf2(f0.z, f0.w);
            pk.u.z = pack_bf2(f1.x, f1.y);
            pk.u.w = pack_bf2(f1.z, f1.w);
            a = pk.s;
        } else {
            const unsigned short* Ab = (const unsigned short*)Avoid;
            a = *(const short8*)(Ab + (size_t)arow * K + kc + quad * 8);
        }
#pragma unroll
        for (int nt = 0; nt < NT; ++nt) {
            short8 b = *(const short8*)(BT + (size_t)(nt * 16 + mi) * K + kc + quad * 8);
            acc[nt] = __builtin_amdgcn_mfma_f32_16x16x32_bf16(a, b, acc[nt], 0, 0, 0);
        }
    }

    // epilogue: D layout col=lane&15 (=mi -> gn), row=quad*4+r (-> gm)
#pragma unroll
    for (int nt = 0; nt < NT; ++nt) {
        floatx4 v = acc[nt];
        int gn = nt * 16 + mi;
#pragma unroll
        for (int r = 0; r < 4; ++r) {
            int gm = m0 + quad * 4 + r;
            if (gm >= M) continue;
            float val = v[r];
            if (EPI == 0) {
                C0[(size_t)gm * 128 + gn] = f2bf(rowscale[gm] * val);
            } else {
                val += bias[gn];
                if (gn < 128)      C0[(size_t)gm * 128 + gn] = f2bf(fmaxf(val, 0.f));
                else if (gn < 168) C1[(size_t)gm * 40 + (gn - 128)] = val;
                else if (gn < 170) C2[(size_t)gm * 2 + (gn - 168)] = val;
            }
        }
    }
}

// ------------------------------------------------------------------
// mega1: blocks with bid%9==0 run the input GEMM; the rest run deg_rank
// (1 packed 64-bit atomic per edge; return value = rank within dst).
// ------------------------------------------------------------------
__global__ __launch_bounds__(256) void mega1(
    const float* __restrict__ x, const unsigned short* __restrict__ WcatT,
    unsigned short* __restrict__ h0, float* __restrict__ wide, float* __restrict__ attnL,
    const float* __restrict__ bcat,
    const int* __restrict__ ei, const float* __restrict__ ew,
    unsigned long long* __restrict__ packed, int* __restrict__ rank, int M, int e) {
    int bid = blockIdx.x;
    int q = bid / 9;
    if (bid - q * 9 == 0) {
        gemm_body<1, 12, 1>(q, x, WcatT, M, 512, h0, wide, attnL, bcat, nullptr);
    } else {
        int i = (bid - q - 1) * 256 + threadIdx.x;
        if (i < e) {
            int d = ei[e + i];               // dst = edge_index[1]
            unsigned fx = (unsigned)(ew[i] * FXS);
            unsigned long long old =
                atomicAdd(&packed[d], (1ull << 40) | (unsigned long long)fx);
            rank[i] = (int)(old >> 40);
        }
    }
}

// ------------------------------------------------------------------
// mega2: bid%9==0 -> conv1 GEMM (rowscale=dinv); rest -> fill edges
// (no atomics: slot = ptr[d] + rank[i], record packs (src, ew)).
// ------------------------------------------------------------------
__global__ __launch_bounds__(256) void mega2(
    const unsigned short* __restrict__ h0, const unsigned short* __restrict__ Wc1T,
    unsigned short* __restrict__ tmpB, const float* __restrict__ dinv,
    const int* __restrict__ ei, const float* __restrict__ ew,
    const int* __restrict__ ptr, const int* __restrict__ rank,
    uint2* __restrict__ edges, int M, int e) {
    int bid = blockIdx.x;
    int q = bid / 9;
    if (bid - q * 9 == 0) {
        gemm_body<0, 8, 0>(q, h0, Wc1T, M, 128, tmpB, nullptr, nullptr, nullptr, dinv);
    } else {
        int i = (bid - q - 1) * 256 + threadIdx.x;
        if (i < e) {
            int r = ei[i];
            int d = ei[e + i];
            edges[ptr[d] + rank[i]] = make_uint2((unsigned)r, __float_as_uint(ew[i]));
        }
    }
}

__global__ __launch_bounds__(256) void gemm_conv(
    const unsigned short* __restrict__ A, const unsigned short* __restrict__ BT,
    unsigned short* __restrict__ C0, const float* __restrict__ rowscale, int M) {
    gemm_body<0, 8, 0>(blockIdx.x, A, BT, M, 128, C0, nullptr, nullptr, nullptr, rowscale);
}

// ------------------------------------------------------------------
// Scan over degree counts + dinv computation fused.
// ------------------------------------------------------------------
__global__ void scan_blocks(const unsigned long long* __restrict__ packed,
                            int* __restrict__ ptr, int* __restrict__ bsum,
                            float* __restrict__ dinv, int n) {
    __shared__ int s[1024];
    int tid = threadIdx.x;
    int i = blockIdx.x * 1024 + tid;
    int v = 0;
    if (i < n) {
        unsigned long long pk = packed[i];
        v = (int)(pk >> 40);
        float deg = 1.0f + (float)(pk & MASK40) * (1.0f / FXS);  // + self-loop
        dinv[i] = rsqrtf(deg);
    }
    s[tid] = v;
    __syncthreads();
    for (int off = 1; off < 1024; off <<= 1) {
        int t = (tid >= off) ? s[tid - off] : 0;
        __syncthreads();
        s[tid] += t;
        __syncthreads();
    }
    if (i < n) ptr[i] = s[tid] - v;              // exclusive
    if (tid == 1023) bsum[blockIdx.x] = s[1023];
}

__global__ void scan_bsums(int* bsum, int nb) {
    __shared__ int s[1024];
    int tid = threadIdx.x;
    int v = (tid < nb) ? bsum[tid] : 0;
    s[tid] = v;
    __syncthreads();
    for (int off = 1; off < 1024; off <<= 1) {
        int t = (tid >= off) ? s[tid - off] : 0;
        __syncthreads();
        s[tid] += t;
        __syncthreads();
    }
    if (tid < nb) bsum[tid] = s[tid] - v;        // exclusive
}

__global__ void scan_add(int* __restrict__ ptr, const int* __restrict__ bsum,
                         int n, int total) {
    int i = blockIdx.x * 1024 + threadIdx.x;
    if (i < n) ptr[i] += bsum[blockIdx.x];
    if (i == 0) ptr[n] = total;
}

// ------------------------------------------------------------------
// GCN propagation, dst-CSR, bf16 messages, dinv pre-folded into rows:
// out[d] = relu(dinv[d] * (tmp'[d] + sum ew*tmp'[src]) + bias)
// One WAVE per dst node, 8-deep edge unroll for MLP.
// ------------------------------------------------------------------
__global__ __launch_bounds__(256) void propagate(
    const unsigned int* __restrict__ tmp2,    // [M][64] packed bf16x2 (dinv-scaled)
    unsigned int* __restrict__ out2,
    const float* __restrict__ bias, const float* __restrict__ dinv,
    const int* __restrict__ ptr, const uint2* __restrict__ edges, int n) {
    int wave = threadIdx.x >> 6, lane = threadIdx.x & 63;
    int d = blockIdx.x * 4 + wave;
    if (d >= n) return;

    unsigned u = tmp2[(size_t)d * 64 + lane];   // self loop
    float acc0 = bflo(u);
    float acc1 = bfhi(u);

    int p = ptr[d], p1 = ptr[d + 1];
    for (; p + 8 <= p1; p += 8) {
        uint2 q[8];
#pragma unroll
        for (int j = 0; j < 8; ++j) q[j] = edges[p + j];
        unsigned rv[8];
#pragma unroll
        for (int j = 0; j < 8; ++j) rv[j] = tmp2[(size_t)q[j].x * 64 + lane];
#pragma unroll
        for (int j = 0; j < 8; ++j) {
            float w = __uint_as_float(q[j].y);
            acc0 += w * bflo(rv[j]); acc1 += w * bfhi(rv[j]);
        }
    }
    for (; p < p1; ++p) {
        uint2 q = edges[p];
        unsigned a = tmp2[(size_t)q.x * 64 + lane];
        float w = __uint_as_float(q.y);
        acc0 += w * bflo(a); acc1 += w * bfhi(a);
    }
    float di = dinv[d];
    float v0 = fmaxf(di * acc0 + bias[2 * lane], 0.f);
    float v1 = fmaxf(di * acc1 + bias[2 * lane + 1], 0.f);
    out2[(size_t)d * 64 + lane] = (unsigned)f2bf(v0) | ((unsigned)f2bf(v1) << 16);
}

// ------------------------------------------------------------------
// Final: out = (h2 @ W2 + b2) * a0 + wide * a1, attn = softmax(logits)
// ------------------------------------------------------------------
__global__ void final_k(const unsigned short* __restrict__ h2, const float* __restrict__ wide,
                        const float* __restrict__ attnL, const float* __restrict__ W2,
                        const float* __restrict__ b2, float* __restrict__ out) {
    __shared__ __align__(16) float hs[8][132];
    __shared__ __align__(16) float w2t[40][132];
    int tid = threadIdx.x;
    int m0 = blockIdx.x * 8;

    for (int idx = tid; idx < 8 * 128; idx += 320) {
        hs[idx >> 7][idx & 127] = bf2f(h2[(size_t)m0 * 128 + idx]);
    }
    for (int idx = tid; idx < 40 * 128; idx += 320) {
        int c = idx >> 7, k = idx & 127;
        w2t[c][k] = W2[k * 40 + c];
    }
    __syncthreads();

    int c = tid % 40;
    int nl = tid / 40;
    float acc = 0.f;
#pragma unroll
    for (int k = 0; k < 128; k += 4) {
        float4 h4 = *(const float4*)&hs[nl][k];
        float4 w4 = *(const float4*)&w2t[c][k];
        acc += h4.x * w4.x + h4.y * w4.y + h4.z * w4.z + h4.w * w4.w;
    }
    int m = m0 + nl;
    float l0 = attnL[m * 2], l1 = attnL[m * 2 + 1];
    float mx = fmaxf(l0, l1);
    float e0 = __expf(l0 - mx), e1 = __expf(l1 - mx);
    float inv = 1.f / (e0 + e1);
    out[(size_t)m * 40 + c] = (acc + b2[c]) * (e0 * inv) + wide[(size_t)m * 40 + c] * (e1 * inv);
}

// ------------------------------------------------------------------
extern "C" void kernel_launch(void* const* d_in, const int* in_sizes, int n_in,
                              void* d_out, int out_size, void* d_ws, size_t ws_size,
                              hipStream_t stream) {
    (void)in_sizes; (void)n_in; (void)out_size; (void)ws_size;
    const float* x   = (const float*)d_in[0];
    const int*   ei  = (const int*)d_in[1];
    const float* ew  = (const float*)d_in[2];
    const float* W1  = (const float*)d_in[3];
    const float* b1  = (const float*)d_in[4];
    const float* Wc1 = (const float*)d_in[5];
    const float* bc1 = (const float*)d_in[6];
    const float* Wc2 = (const float*)d_in[7];
    const float* bc2 = (const float*)d_in[8];
    const float* W2  = (const float*)d_in[9];
    const float* b2  = (const float*)d_in[10];
    const float* Ww  = (const float*)d_in[11];
    const float* bw  = (const float*)d_in[12];
    const float* Wa  = (const float*)d_in[13];
    const float* ba  = (const float*)d_in[14];
    float* out = (float*)d_out;

    const int N = N_NODES, E = N_EDGES;
    char* ws = (char*)d_ws;
    size_t off = 0;
    auto alloc = [&](size_t bytes) -> void* {
        void* p = ws + off;
        off = (off + bytes + 255) & ~(size_t)255;
        return p;
    };
    unsigned short* bufA = (unsigned short*)alloc((size_t)N * 128 * 2);
    unsigned short* bufB = (unsigned short*)alloc((size_t)N * 128 * 2);
    float* wide  = (float*)alloc((size_t)N * 40 * 4);
    float* attnL = (float*)alloc((size_t)N * 2 * 4);
    float* dinv  = (float*)alloc((size_t)N * 4);
    unsigned long long* packed = (unsigned long long*)alloc((size_t)N * 8);
    int*   ptr   = (int*)alloc((size_t)(N + 1) * 4);
    int*   rank  = (int*)alloc((size_t)E * 4);
    int*   bsum  = (int*)alloc(1024 * 4);
    uint2* edges = (uint2*)alloc((size_t)E * 8);
    unsigned short* WcatT = (unsigned short*)alloc((size_t)192 * 512 * 2);
    unsigned short* Wc1T  = (unsigned short*)alloc((size_t)128 * 128 * 2);
    unsigned short* Wc2T  = (unsigned short*)alloc((size_t)128 * 128 * 2);
    float* bcat  = (float*)alloc(192 * 4);

    const int MB = (N + 63) / 64;          // 1563 gemm m-blocks
    const int MEGA = MB * 9;               // >= MB + 12500 edge blocks, 1:8

    // setup: weight packs + packed[] zero-init
    setup_misc<<<320 + (N + 255) / 256, 256, 0, stream>>>(
        W1, b1, Ww, bw, Wa, ba, Wc1, Wc2, WcatT, bcat, Wc1T, Wc2T, packed, N);

    // mega1: input GEMM (x -> h0/wide/attnL) overlapped with deg_rank atomics
    mega1<<<MEGA, 256, 0, stream>>>(x, WcatT, bufA, wide, attnL, bcat,
                                    ei, ew, packed, rank, N, E);

    // scans (+ dinv)
    int nb = (N + 1023) / 1024;
    scan_blocks<<<nb, 1024, 0, stream>>>(packed, ptr, bsum, dinv, N);
    scan_bsums<<<1, 1024, 0, stream>>>(bsum, nb);
    scan_add<<<nb, 1024, 0, stream>>>(ptr, bsum, N, E);

    // mega2: conv1 GEMM (h0 -> tmpB, dinv-scaled) overlapped with edge fill
    mega2<<<MEGA, 256, 0, stream>>>(bufA, Wc1T, bufB, dinv, ei, ew, ptr, rank, edges, N, E);
    propagate<<<(N + 3) / 4, 256, 0, stream>>>((const unsigned int*)bufB, (unsigned int*)bufA,
                                               bc1, dinv, ptr, edges, N);

    // conv layer 2
    gemm_conv<<<MB, 256, 0, stream>>>(bufA, Wc2T, bufB, dinv, N);
    propagate<<<(N + 3) / 4, 256, 0, stream>>>((const unsigned int*)bufB, (unsigned int*)bufA,
                                               bc2, dinv, ptr, edges, N);

    // final fusion
    final_k<<<N / 8, 320, 0, stream>>>(bufA, wide, attnL, W2, b2, out);
}